// Round 1
// baseline (332.774 us; speedup 1.0000x reference)
//
#include <hip/hip_runtime.h>
#include <hip/hip_fp16.h>

// Problem constants (from reference): B=2, N=512, D=256, H=8, L=3
#define BB 2
#define NNq 512
#define DDm 256
#define HHh 8
#define DHh 32
#define LLn 3

static constexpr float EPSF   = 1e-4f;
static constexpr float INV2PI = 0.15915494309189535f;   // 1/(2*pi)
static constexpr float SCALE  = 0.17677669529663687f;   // 1/sqrt(32)

#if __has_builtin(__builtin_amdgcn_fractf)
#define FRACTF(x) __builtin_amdgcn_fractf(x)
#else
#define FRACTF(x) ((x) - floorf(x))
#endif
#if __has_builtin(__builtin_amdgcn_sinf)
#define SINR(x) __builtin_amdgcn_sinf(x)   // sin(2*pi*x), x in revolutions
#define COSR(x) __builtin_amdgcn_cosf(x)
#else
#define SINR(x) __sinf((x) * 6.2831853071795865f)
#define COSR(x) __cosf((x) * 6.2831853071795865f)
#endif

struct __align__(8) H4 { __half a, b, c, d; };

// ---------------------------------------------------------------- boxprep
__global__ __launch_bounds__(256) void k_boxprep(const float* __restrict__ boxes,
                                                 float* __restrict__ boxp) {
    int idx = blockIdx.x * 256 + threadIdx.x;
    if (idx >= BB * NNq) return;
    float4 bx = reinterpret_cast<const float4*>(boxes)[idx];
    float cx = 0.5f * (bx.x + bx.z), cy = 0.5f * (bx.y + bx.w);
    float w = fmaxf(bx.z - bx.x, EPSF), h = fmaxf(bx.w - bx.y, EPSF);
    reinterpret_cast<float4*>(boxp)[idx] = make_float4(cx, cy, w, h);
}

// ---------------------------------------------------------------- geo
// Per pair (b,i,j): rel[4] -> 128 angles -> sin/cos -> contract with Wg for
// all L*H = 24 outputs. Store geo = relu(emb@Wg + bg) as fp16:
// layout geo[(l*8+h)][b][i][j].
__device__ inline void pair_rel(const float* __restrict__ boxp, int p,
                                float rel[4], int& b, int& i, int& j) {
    b = p >> 18;                     // N*N = 2^18
    int rem = p & (NNq * NNq - 1);
    i = rem >> 9;                    // N = 2^9
    j = rem & (NNq - 1);
    float4 bi = reinterpret_cast<const float4*>(boxp)[b * NNq + i];
    float4 bj = reinterpret_cast<const float4*>(boxp)[b * NNq + j];
    rel[0] = __logf(fabsf(bj.x - bi.x) / bj.z + EPSF);
    rel[1] = __logf(fabsf(bj.y - bi.y) / bj.w + EPSF);
    rel[2] = __logf(bi.z / bj.z + EPSF);
    rel[3] = __logf(bi.w / bj.w + EPSF);
}

__global__ __launch_bounds__(256) void k_geo(const float* __restrict__ boxp,
                                             const float* __restrict__ Wg,
                                             const float* __restrict__ bg,
                                             const float* __restrict__ divm,
                                             __half* __restrict__ geo) {
    __shared__ float wg[6144];     // [c][f][48]: 24 sin-weights then 24 cos-weights (t = l*8+h)
    __shared__ float invdiv[32];
    __shared__ float bgl[24];
    int tid = threadIdx.x;
    for (int u = tid; u < 6144; u += 256) {
        int cf = u / 48, r = u % 48;
        int c = cf >> 5, f = cf & 31;
        int rr = (r < 24) ? r : r - 24;
        int l = rr >> 3, hh = rr & 7;
        int d = c * 64 + ((r < 24) ? f : 32 + f);
        wg[u] = Wg[(size_t)l * DDm * HHh + (size_t)d * HHh + hh];
    }
    if (tid < 32) invdiv[tid] = INV2PI / divm[tid];
    if (tid < 24) bgl[tid] = bg[tid];
    __syncthreads();

    int p0 = blockIdx.x * 512 + tid;   // pair 0; pair 1 = p0 + 256
    int p1 = p0 + 256;
    float rel0[4], rel1[4];
    int b0, i0, j0, b1, i1, j1;
    pair_rel(boxp, p0, rel0, b0, i0, j0);
    pair_rel(boxp, p1, rel1, b1, i1, j1);

    float acc0[24], acc1[24];
#pragma unroll
    for (int t = 0; t < 24; ++t) { acc0[t] = 0.f; acc1[t] = 0.f; }

#pragma unroll
    for (int c = 0; c < 4; ++c) {
        float r0 = rel0[c], r1 = rel1[c];
        for (int f = 0; f < 32; ++f) {
            float iv = invdiv[f];
            float rv0 = FRACTF(r0 * iv), rv1 = FRACTF(r1 * iv);
            float s0 = SINR(rv0), co0 = COSR(rv0);
            float s1 = SINR(rv1), co1 = COSR(rv1);
            const float4* wp = reinterpret_cast<const float4*>(&wg[(c * 32 + f) * 48]);
#pragma unroll
            for (int u = 0; u < 6; ++u) {
                float4 aS = wp[u];
                float4 aC = wp[u + 6];
                acc0[u*4+0] = fmaf(s0, aS.x, fmaf(co0, aC.x, acc0[u*4+0]));
                acc0[u*4+1] = fmaf(s0, aS.y, fmaf(co0, aC.y, acc0[u*4+1]));
                acc0[u*4+2] = fmaf(s0, aS.z, fmaf(co0, aC.z, acc0[u*4+2]));
                acc0[u*4+3] = fmaf(s0, aS.w, fmaf(co0, aC.w, acc0[u*4+3]));
                acc1[u*4+0] = fmaf(s1, aS.x, fmaf(co1, aC.x, acc1[u*4+0]));
                acc1[u*4+1] = fmaf(s1, aS.y, fmaf(co1, aC.y, acc1[u*4+1]));
                acc1[u*4+2] = fmaf(s1, aS.z, fmaf(co1, aC.z, acc1[u*4+2]));
                acc1[u*4+3] = fmaf(s1, aS.w, fmaf(co1, aC.w, acc1[u*4+3]));
            }
        }
    }

    size_t plane = (size_t)NNq * NNq;
#pragma unroll
    for (int t = 0; t < 24; ++t) {
        float g0 = fmaxf(acc0[t] + bgl[t], 0.f);
        float g1 = fmaxf(acc1[t] + bgl[t], 0.f);
        geo[(size_t)(t * BB + b0) * plane + (size_t)i0 * NNq + j0] = __float2half(g0);
        geo[(size_t)(t * BB + b1) * plane + (size_t)i1 * NNq + j1] = __float2half(g1);
    }
}

// ---------------------------------------------------------------- GEMM
// C[z] = relu(A @ W[z] + bias[z]) (+ resid). M x 256 @ 256 x 256.
// Tile 64x64, BK=16, 256 threads, 4x4 per thread.
__global__ __launch_bounds__(256) void k_gemm(const float* __restrict__ A,
        const float* __restrict__ W0, const float* __restrict__ W1, const float* __restrict__ W2,
        const float* __restrict__ b0, const float* __restrict__ b1, const float* __restrict__ b2,
        float* __restrict__ C0, float* __restrict__ C1, float* __restrict__ C2,
        const float* __restrict__ resid) {
    const float* W   = (blockIdx.z == 0) ? W0 : (blockIdx.z == 1) ? W1 : W2;
    const float* bia = (blockIdx.z == 0) ? b0 : (blockIdx.z == 1) ? b1 : b2;
    float*       C   = (blockIdx.z == 0) ? C0 : (blockIdx.z == 1) ? C1 : C2;

    __shared__ float As[64][17];
    __shared__ float Bs[16][64];
    int tid = threadIdx.x;
    int tx = tid & 15, ty = tid >> 4;
    int m0 = blockIdx.x * 64, n0 = blockIdx.y * 64;
    float acc[4][4] = {};

    int arow = tid >> 2, ac4 = (tid & 3) * 4;
    int bk = tid >> 4, bn4 = (tid & 15) * 4;

    for (int k0 = 0; k0 < 256; k0 += 16) {
        float4 av = *reinterpret_cast<const float4*>(&A[(size_t)(m0 + arow) * 256 + k0 + ac4]);
        As[arow][ac4 + 0] = av.x; As[arow][ac4 + 1] = av.y;
        As[arow][ac4 + 2] = av.z; As[arow][ac4 + 3] = av.w;
        *reinterpret_cast<float4*>(&Bs[bk][bn4]) =
            *reinterpret_cast<const float4*>(&W[(size_t)(k0 + bk) * 256 + n0 + bn4]);
        __syncthreads();
#pragma unroll
        for (int k = 0; k < 16; ++k) {
            float4 bv = *reinterpret_cast<const float4*>(&Bs[k][tx * 4]);
#pragma unroll
            for (int e = 0; e < 4; ++e) {
                float a = As[ty * 4 + e][k];
                acc[e][0] = fmaf(a, bv.x, acc[e][0]);
                acc[e][1] = fmaf(a, bv.y, acc[e][1]);
                acc[e][2] = fmaf(a, bv.z, acc[e][2]);
                acc[e][3] = fmaf(a, bv.w, acc[e][3]);
            }
        }
        __syncthreads();
    }

    float4 bias4 = *reinterpret_cast<const float4*>(&bia[n0 + tx * 4]);
#pragma unroll
    for (int e = 0; e < 4; ++e) {
        int row = m0 + ty * 4 + e;
        float4 o;
        o.x = fmaxf(acc[e][0] + bias4.x, 0.f);
        o.y = fmaxf(acc[e][1] + bias4.y, 0.f);
        o.z = fmaxf(acc[e][2] + bias4.z, 0.f);
        o.w = fmaxf(acc[e][3] + bias4.w, 0.f);
        if (resid) {
            float4 rv = *reinterpret_cast<const float4*>(&resid[(size_t)row * 256 + n0 + tx * 4]);
            o.x += rv.x; o.y += rv.y; o.z += rv.z; o.w += rv.w;
        }
        *reinterpret_cast<float4*>(&C[(size_t)row * 256 + n0 + tx * 4]) = o;
    }
}

// ---------------------------------------------------------------- scores
// S[b,h,i,j] = (q_h[i] . k_h[j]) * SCALE + log(geo + 1e-6), masked.
// Block: (b,h) x i-tile 32 x j-tile 128. K = 32.
__global__ __launch_bounds__(256) void k_score(const float* __restrict__ q,
                                               const float* __restrict__ k,
                                               const __half* __restrict__ geo,
                                               const int* __restrict__ mask,
                                               float* __restrict__ S, int l) {
    int bh = blockIdx.z;
    int b = bh >> 3, h = bh & 7;
    int i0t = blockIdx.y * 32, j0t = blockIdx.x * 128;
    __shared__ float Qs[32][36];
    __shared__ float Kst[32][132];   // [d][j]
    int tid = threadIdx.x;
    {
        int i = tid >> 3, d4 = (tid & 7) * 4;
        float4 qv = *reinterpret_cast<const float4*>(
            &q[(size_t)(b * NNq + i0t + i) * DDm + h * DHh + d4]);
        *reinterpret_cast<float4*>(&Qs[i][d4]) = qv;
    }
#pragma unroll
    for (int r = 0; r < 4; ++r) {
        int idx = r * 256 + tid;
        int j = idx >> 3, d4 = (idx & 7) * 4;
        float4 kv = *reinterpret_cast<const float4*>(
            &k[(size_t)(b * NNq + j0t + j) * DDm + h * DHh + d4]);
        Kst[d4 + 0][j] = kv.x; Kst[d4 + 1][j] = kv.y;
        Kst[d4 + 2][j] = kv.z; Kst[d4 + 3][j] = kv.w;
    }
    __syncthreads();

    int tx = tid & 31, ty = tid >> 5;
    int i0 = ty * 4, j0 = tx * 4;
    float acc[4][4] = {};
#pragma unroll 8
    for (int d = 0; d < 32; ++d) {
        float4 kv = *reinterpret_cast<const float4*>(&Kst[d][j0]);
#pragma unroll
        for (int e = 0; e < 4; ++e) {
            float a = Qs[i0 + e][d];
            acc[e][0] = fmaf(a, kv.x, acc[e][0]);
            acc[e][1] = fmaf(a, kv.y, acc[e][1]);
            acc[e][2] = fmaf(a, kv.z, acc[e][2]);
            acc[e][3] = fmaf(a, kv.w, acc[e][3]);
        }
    }

    int plane = l * 8 + h;
    size_t pl = (size_t)NNq * NNq;
#pragma unroll
    for (int e = 0; e < 4; ++e) {
        int ig = i0t + i0 + e;
        int jg = j0t + j0;
        H4 g4 = *reinterpret_cast<const H4*>(
            &geo[(size_t)(plane * BB + b) * pl + (size_t)ig * NNq + jg]);
        int4 mv = *reinterpret_cast<const int4*>(&mask[(size_t)(b * NNq + ig) * NNq + jg]);
        float4 sv;
        sv.x = acc[e][0] * SCALE + __logf(__half2float(g4.a) + 1e-6f);
        sv.y = acc[e][1] * SCALE + __logf(__half2float(g4.b) + 1e-6f);
        sv.z = acc[e][2] * SCALE + __logf(__half2float(g4.c) + 1e-6f);
        sv.w = acc[e][3] * SCALE + __logf(__half2float(g4.d) + 1e-6f);
        if (mv.x == 0) sv.x = -1e9f;
        if (mv.y == 0) sv.y = -1e9f;
        if (mv.z == 0) sv.z = -1e9f;
        if (mv.w == 0) sv.w = -1e9f;
        *reinterpret_cast<float4*>(&S[((size_t)(b * HHh + h) * NNq + ig) * NNq + jg]) = sv;
    }
}

// ---------------------------------------------------------------- softmax (rows of 512)
__global__ __launch_bounds__(256) void k_softmax(float* __restrict__ S) {
    int row = blockIdx.x * 4 + (threadIdx.x >> 6);
    int lane = threadIdx.x & 63;
    float4* rp = reinterpret_cast<float4*>(S + (size_t)row * NNq);
    float4 v0 = rp[lane], v1 = rp[lane + 64];
    float mx = fmaxf(fmaxf(fmaxf(v0.x, v0.y), fmaxf(v0.z, v0.w)),
                     fmaxf(fmaxf(v1.x, v1.y), fmaxf(v1.z, v1.w)));
#pragma unroll
    for (int o = 32; o > 0; o >>= 1) mx = fmaxf(mx, __shfl_xor(mx, o, 64));
    v0.x = __expf(v0.x - mx); v0.y = __expf(v0.y - mx);
    v0.z = __expf(v0.z - mx); v0.w = __expf(v0.w - mx);
    v1.x = __expf(v1.x - mx); v1.y = __expf(v1.y - mx);
    v1.z = __expf(v1.z - mx); v1.w = __expf(v1.w - mx);
    float sum = v0.x + v0.y + v0.z + v0.w + v1.x + v1.y + v1.z + v1.w;
#pragma unroll
    for (int o = 32; o > 0; o >>= 1) sum += __shfl_xor(sum, o, 64);
    float inv = 1.0f / sum;
    v0.x *= inv; v0.y *= inv; v0.z *= inv; v0.w *= inv;
    v1.x *= inv; v1.y *= inv; v1.z *= inv; v1.w *= inv;
    rp[lane] = v0; rp[lane + 64] = v1;
}

// ---------------------------------------------------------------- PV
// y[b,i,h*32+d] = sum_j P[b,h,i,j] * v[b,j,h*32+d]. Block: (b,h) x i-tile 64.
__global__ __launch_bounds__(256) void k_pv(const float* __restrict__ P,
                                            const float* __restrict__ v,
                                            float* __restrict__ y) {
    int bh = blockIdx.y;
    int b = bh >> 3, h = bh & 7;
    int i0t = blockIdx.x * 64;
    __shared__ float Ps[64][65];
    __shared__ float Vs[64][36];
    int tid = threadIdx.x;
    int tx = tid & 7, ty = tid >> 3;
    int d4 = tx * 4, i0 = ty * 2;
    float acc[2][4] = {};

    for (int j0 = 0; j0 < NNq; j0 += 64) {
#pragma unroll
        for (int r = 0; r < 4; ++r) {
            int idx = r * 1024 + tid * 4;
            int i = idx >> 6, j4 = idx & 63;
            float4 p4 = *reinterpret_cast<const float4*>(
                &P[((size_t)(b * HHh + h) * NNq + i0t + i) * NNq + j0 + j4]);
            Ps[i][j4 + 0] = p4.x; Ps[i][j4 + 1] = p4.y;
            Ps[i][j4 + 2] = p4.z; Ps[i][j4 + 3] = p4.w;
        }
#pragma unroll
        for (int r = 0; r < 2; ++r) {
            int idx = r * 1024 + tid * 4;
            int j = idx >> 5, dd4 = idx & 31;
            float4 vv = *reinterpret_cast<const float4*>(
                &v[(size_t)(b * NNq + j0 + j) * DDm + h * DHh + dd4]);
            *reinterpret_cast<float4*>(&Vs[j][dd4]) = vv;
        }
        __syncthreads();
#pragma unroll 8
        for (int j = 0; j < 64; ++j) {
            float4 vv = *reinterpret_cast<const float4*>(&Vs[j][d4]);
            float a0 = Ps[i0][j], a1 = Ps[i0 + 1][j];
            acc[0][0] = fmaf(a0, vv.x, acc[0][0]);
            acc[0][1] = fmaf(a0, vv.y, acc[0][1]);
            acc[0][2] = fmaf(a0, vv.z, acc[0][2]);
            acc[0][3] = fmaf(a0, vv.w, acc[0][3]);
            acc[1][0] = fmaf(a1, vv.x, acc[1][0]);
            acc[1][1] = fmaf(a1, vv.y, acc[1][1]);
            acc[1][2] = fmaf(a1, vv.z, acc[1][2]);
            acc[1][3] = fmaf(a1, vv.w, acc[1][3]);
        }
        __syncthreads();
    }
#pragma unroll
    for (int e = 0; e < 2; ++e) {
        *reinterpret_cast<float4*>(
            &y[(size_t)(b * NNq + i0t + i0 + e) * DDm + h * DHh + d4]) =
            make_float4(acc[e][0], acc[e][1], acc[e][2], acc[e][3]);
    }
}

// ---------------------------------------------------------------- launch
extern "C" void kernel_launch(void* const* d_in, const int* in_sizes, int n_in,
                              void* d_out, int out_size, void* d_ws, size_t ws_size,
                              hipStream_t stream) {
    const float* boxes    = (const float*)d_in[0];
    const float* features = (const float*)d_in[1];
    const int*   mask     = (const int*)d_in[2];
    const float* Wq = (const float*)d_in[3];
    const float* bq = (const float*)d_in[4];
    const float* Wk = (const float*)d_in[5];
    const float* bk = (const float*)d_in[6];
    const float* Wv = (const float*)d_in[7];
    const float* bv = (const float*)d_in[8];
    const float* Wo = (const float*)d_in[9];
    const float* bo = (const float*)d_in[10];
    const float* Wg = (const float*)d_in[11];
    const float* bg = (const float*)d_in[12];
    const float* dv = (const float*)d_in[13];

    char* ws = (char*)d_ws;
    // workspace layout (bytes)
    float*  boxp = (float*)(ws);                              //    16,384
    __half* geo  = (__half*)(ws + 16384);                     // 25,165,824
    float*  qb   = (float*)(ws + 25182208);                   //  1,048,576
    float*  kb   = (float*)(ws + 26230784);                   //  1,048,576
    float*  vb   = (float*)(ws + 27279360);                   //  1,048,576
    float*  yb   = (float*)(ws + 28327936);                   //  1,048,576
    float*  Sb   = (float*)(ws + 29376512);                   // 16,777,216  -> total ~46.2 MB
    float*  x    = (float*)d_out;

    hipMemcpyAsync(x, features, (size_t)BB * NNq * DDm * sizeof(float),
                   hipMemcpyDeviceToDevice, stream);
    k_boxprep<<<dim3((BB * NNq + 255) / 256), dim3(256), 0, stream>>>(boxes, boxp);
    k_geo<<<dim3(1024), dim3(256), 0, stream>>>(boxp, Wg, bg, dv, geo);

    for (int l = 0; l < LLn; ++l) {
        const float* Wq_l = Wq + (size_t)l * DDm * DDm;
        const float* Wk_l = Wk + (size_t)l * DDm * DDm;
        const float* Wv_l = Wv + (size_t)l * DDm * DDm;
        const float* Wo_l = Wo + (size_t)l * DDm * DDm;
        const float* bq_l = bq + (size_t)l * DDm;
        const float* bk_l = bk + (size_t)l * DDm;
        const float* bv_l = bv + (size_t)l * DDm;
        const float* bo_l = bo + (size_t)l * DDm;

        k_gemm<<<dim3(16, 4, 3), dim3(256), 0, stream>>>(
            x, Wq_l, Wk_l, Wv_l, bq_l, bk_l, bv_l, qb, kb, vb, nullptr);
        k_score<<<dim3(4, 16, 16), dim3(256), 0, stream>>>(qb, kb, geo, mask, Sb, l);
        k_softmax<<<dim3(BB * HHh * NNq / 4), dim3(256), 0, stream>>>(Sb);
        k_pv<<<dim3(8, 16), dim3(256), 0, stream>>>(Sb, vb, yb);
        k_gemm<<<dim3(16, 4, 1), dim3(256), 0, stream>>>(
            yb, Wo_l, Wo_l, Wo_l, bo_l, bo_l, bo_l, x, x, x, x);
    }
}

// Round 4
// 300.305 us; speedup vs baseline: 1.1081x; 1.1081x over previous
//
#include <hip/hip_runtime.h>
#include <hip/hip_fp16.h>

// Problem constants (from reference): B=2, N=512, D=256, H=8, L=3
#define BB 2
#define NNq 512
#define DDm 256
#define HHh 8
#define DHh 32
#define LLn 3

static constexpr float EPSF   = 1e-4f;
static constexpr float INV2PI = 0.15915494309189535f;   // 1/(2*pi)
static constexpr float SCALE  = 0.17677669529663687f;   // 1/sqrt(32)

#if __has_builtin(__builtin_amdgcn_fractf)
#define FRACTF(x) __builtin_amdgcn_fractf(x)
#else
#define FRACTF(x) ((x) - floorf(x))
#endif
#if __has_builtin(__builtin_amdgcn_sinf)
#define SINR(x) __builtin_amdgcn_sinf(x)   // sin(2*pi*x), x in revolutions
#define COSR(x) __builtin_amdgcn_cosf(x)
#else
#define SINR(x) __sinf((x) * 6.2831853071795865f)
#define COSR(x) __cosf((x) * 6.2831853071795865f)
#endif

struct __align__(8) H4 { __half a, b, c, d; };

typedef _Float16 f16x8 __attribute__((ext_vector_type(8)));
typedef float    f32x4 __attribute__((ext_vector_type(4)));

// ---------------------------------------------------------------- boxprep
__global__ __launch_bounds__(256) void k_boxprep(const float* __restrict__ boxes,
                                                 float* __restrict__ boxp) {
    int idx = blockIdx.x * 256 + threadIdx.x;
    if (idx >= BB * NNq) return;
    float4 bx = reinterpret_cast<const float4*>(boxes)[idx];
    float cx = 0.5f * (bx.x + bx.z), cy = 0.5f * (bx.y + bx.w);
    float w = fmaxf(bx.z - bx.x, EPSF), h = fmaxf(bx.w - bx.y, EPSF);
    reinterpret_cast<float4*>(boxp)[idx] = make_float4(cx, cy, w, h);
}

// ---------------------------------------------------------------- geo (MFMA, fp16)
// geo[t][b][i][j] = relu(emb(b,i,j) @ Wg[:,t] + bg[t]),  t = l*8 + h  (24 outputs).
// GEMM view: M = B*N*N pairs, K = 256 (emb dim), N = 24 (padded 32).
// A-frag (emb) built in registers in fp16: lane holds row m = lane&15,
// k = kc*32 + (lane>>4)*8 + j  (j=0..7).  Same k-formula used for B-frag, so
// any HW-internal k permutation cancels.  C/D: col = lane&15,
// row = (lane>>4)*4 + reg  [m89-verified, dtype-independent].
//
// SWIZZLE FIX (round-3 bug): staging XORs the FULL k with mask=(n&7)<<3, whose
// bit 5 flips the low bit of the 32-wide chunk index kc when n&4. The read must
// apply the SAME involution: base uses (kgrp*8 ^ (mask&24)); per-chunk offset
// uses (kc*32) ^ (mask&32). Previously the read added kc*32 outside the XOR,
// so heads with n&4 fetched the kc^1 chunk (sin/cos weights swapped) ->
// dtype-independent absmax 0.273 in rounds 2 and 3.
__global__ __launch_bounds__(256) void k_geo(const float* __restrict__ boxp,
                                             const float* __restrict__ Wg,
                                             const float* __restrict__ bg,
                                             const float* __restrict__ divm,
                                             __half* __restrict__ geo) {
    __shared__ _Float16 WgT[32 * 256];   // [n][k] fp16, k XOR-swizzled by (n&7)<<3
    const int tid = threadIdx.x;
    // stage Wg -> WgT (fp16, transposed, swizzled); n>=24 zero-padded
    for (int idx = tid; idx < 32 * 256; idx += 256) {
        int n = idx >> 8, k = idx & 255;
        float w = (n < 24) ? Wg[(size_t)(n >> 3) * 2048 + (size_t)k * 8 + (n & 7)] : 0.f;
        WgT[n * 256 + (k ^ ((n & 7) << 3))] = (_Float16)w;
    }
    __syncthreads();

    const int lane = tid & 63;
    const int wid  = tid >> 6;
    const int ln15 = lane & 15;
    const int kgrp = lane >> 4;          // 0..3

    // per-lane inv divisors for its 8 f-slots (f0 = kgrp*8)
    float invd[8];
    {
        const float4* dv4 = reinterpret_cast<const float4*>(divm);
        float4 da = dv4[kgrp * 2], db = dv4[kgrp * 2 + 1];
        invd[0] = INV2PI / da.x; invd[1] = INV2PI / da.y;
        invd[2] = INV2PI / da.z; invd[3] = INV2PI / da.w;
        invd[4] = INV2PI / db.x; invd[5] = INV2PI / db.y;
        invd[6] = INV2PI / db.z; invd[7] = INV2PI / db.w;
    }
    const int n0 = ln15;            // output col, tile 0 (always < 24)
    const int n1 = 16 + ln15;       // output col, tile 1 (valid if < 24)
    const float bg0 = bg[n0];
    const float bg1 = (n1 < 24) ? bg[n1] : 0.f;

    // B-frag LDS addressing with the swizzle involution split into disjoint
    // bit-fields. n1&7 == n0&7, so mask/flip are shared.
    const int mask  = (ln15 & 7) << 3;          // bits 3..5
    const int flip5 = mask & 32;                // bit 5 -> flips kc low bit
    const int kb    = (kgrp << 3) ^ (mask & 24);
    const int base0 = n0 * 256 + kb;
    const int base1 = n1 * 256 + kb;

    const float4* boxp4 = reinterpret_cast<const float4*>(boxp);
    const size_t plane = (size_t)NNq * NNq;

    const int base4 = (blockIdx.x * 4 + wid) * 4;   // 4 slabs per wave
#pragma unroll
    for (int it = 0; it < 4; ++it) {
        const int slab = base4 + it;                // 0..32767
        const int p0 = slab << 4;
        const int b  = p0 >> 18;
        const int rem = p0 & (NNq * NNq - 1);
        const int i  = rem >> 9;
        const int j0 = rem & (NNq - 1);

        float4 bi = boxp4[b * NNq + i];
        float4 bj = boxp4[b * NNq + j0 + ln15];     // A-row ln15's key box
        float rel[4];
        rel[0] = __logf(fabsf(bj.x - bi.x) / bj.z + EPSF);
        rel[1] = __logf(fabsf(bj.y - bi.y) / bj.w + EPSF);
        rel[2] = __logf(bi.z / bj.z + EPSF);
        rel[3] = __logf(bi.w / bj.w + EPSF);

        f32x4 acc0 = {0.f, 0.f, 0.f, 0.f};
        f32x4 acc1 = {0.f, 0.f, 0.f, 0.f};

#pragma unroll
        for (int kc = 0; kc < 8; ++kc) {
            const float rc = rel[kc >> 1];
            f16x8 af;
#pragma unroll
            for (int j = 0; j < 8; ++j) {
                float rv = FRACTF(rc * invd[j]);
                af[j] = (_Float16)((kc & 1) ? COSR(rv) : SINR(rv));
            }
            const int koff = (kc * 32) ^ flip5;     // swizzle-correct chunk offset
            f16x8 bf0 = *reinterpret_cast<const f16x8*>(&WgT[base0 + koff]);
            f16x8 bf1 = *reinterpret_cast<const f16x8*>(&WgT[base1 + koff]);
            acc0 = __builtin_amdgcn_mfma_f32_16x16x32_f16(af, bf0, acc0, 0, 0, 0);
            acc1 = __builtin_amdgcn_mfma_f32_16x16x32_f16(af, bf1, acc1, 0, 0, 0);
        }

#pragma unroll
        for (int r = 0; r < 4; ++r) {
            const int m = (kgrp << 2) + r;          // C row = pair within slab
            const int j = j0 + m;
            float g0 = fmaxf(acc0[r] + bg0, 0.f);
            geo[(size_t)(n0 * BB + b) * plane + (size_t)i * NNq + j] = __float2half(g0);
            if (n1 < 24) {
                float g1 = fmaxf(acc1[r] + bg1, 0.f);
                geo[(size_t)(n1 * BB + b) * plane + (size_t)i * NNq + j] = __float2half(g1);
            }
        }
    }
}

// ---------------------------------------------------------------- GEMM
// C[z] = relu(A @ W[z] + bias[z]) (+ resid). M x 256 @ 256 x 256.
// Tile 64x64, BK=16, 256 threads, 4x4 per thread.
__global__ __launch_bounds__(256) void k_gemm(const float* __restrict__ A,
        const float* __restrict__ W0, const float* __restrict__ W1, const float* __restrict__ W2,
        const float* __restrict__ b0, const float* __restrict__ b1, const float* __restrict__ b2,
        float* __restrict__ C0, float* __restrict__ C1, float* __restrict__ C2,
        const float* __restrict__ resid) {
    const float* W   = (blockIdx.z == 0) ? W0 : (blockIdx.z == 1) ? W1 : W2;
    const float* bia = (blockIdx.z == 0) ? b0 : (blockIdx.z == 1) ? b1 : b2;
    float*       C   = (blockIdx.z == 0) ? C0 : (blockIdx.z == 1) ? C1 : C2;

    __shared__ float As[64][17];
    __shared__ float Bs[16][64];
    int tid = threadIdx.x;
    int tx = tid & 15, ty = tid >> 4;
    int m0 = blockIdx.x * 64, n0 = blockIdx.y * 64;
    float acc[4][4] = {};

    int arow = tid >> 2, ac4 = (tid & 3) * 4;
    int bk = tid >> 4, bn4 = (tid & 15) * 4;

    for (int k0 = 0; k0 < 256; k0 += 16) {
        float4 av = *reinterpret_cast<const float4*>(&A[(size_t)(m0 + arow) * 256 + k0 + ac4]);
        As[arow][ac4 + 0] = av.x; As[arow][ac4 + 1] = av.y;
        As[arow][ac4 + 2] = av.z; As[arow][ac4 + 3] = av.w;
        *reinterpret_cast<float4*>(&Bs[bk][bn4]) =
            *reinterpret_cast<const float4*>(&W[(size_t)(k0 + bk) * 256 + n0 + bn4]);
        __syncthreads();
#pragma unroll
        for (int k = 0; k < 16; ++k) {
            float4 bv = *reinterpret_cast<const float4*>(&Bs[k][tx * 4]);
#pragma unroll
            for (int e = 0; e < 4; ++e) {
                float a = As[ty * 4 + e][k];
                acc[e][0] = fmaf(a, bv.x, acc[e][0]);
                acc[e][1] = fmaf(a, bv.y, acc[e][1]);
                acc[e][2] = fmaf(a, bv.z, acc[e][2]);
                acc[e][3] = fmaf(a, bv.w, acc[e][3]);
            }
        }
        __syncthreads();
    }

    float4 bias4 = *reinterpret_cast<const float4*>(&bia[n0 + tx * 4]);
#pragma unroll
    for (int e = 0; e < 4; ++e) {
        int row = m0 + ty * 4 + e;
        float4 o;
        o.x = fmaxf(acc[e][0] + bias4.x, 0.f);
        o.y = fmaxf(acc[e][1] + bias4.y, 0.f);
        o.z = fmaxf(acc[e][2] + bias4.z, 0.f);
        o.w = fmaxf(acc[e][3] + bias4.w, 0.f);
        if (resid) {
            float4 rv = *reinterpret_cast<const float4*>(&resid[(size_t)row * 256 + n0 + tx * 4]);
            o.x += rv.x; o.y += rv.y; o.z += rv.z; o.w += rv.w;
        }
        *reinterpret_cast<float4*>(&C[(size_t)row * 256 + n0 + tx * 4]) = o;
    }
}

// ---------------------------------------------------------------- scores
// S[b,h,i,j] = (q_h[i] . k_h[j]) * SCALE + log(geo + 1e-6), masked.
// Block: (b,h) x i-tile 32 x j-tile 128. K = 32.
__global__ __launch_bounds__(256) void k_score(const float* __restrict__ q,
                                               const float* __restrict__ k,
                                               const __half* __restrict__ geo,
                                               const int* __restrict__ mask,
                                               float* __restrict__ S, int l) {
    int bh = blockIdx.z;
    int b = bh >> 3, h = bh & 7;
    int i0t = blockIdx.y * 32, j0t = blockIdx.x * 128;
    __shared__ float Qs[32][36];
    __shared__ float Kst[32][132];   // [d][j]
    int tid = threadIdx.x;
    {
        int i = tid >> 3, d4 = (tid & 7) * 4;
        float4 qv = *reinterpret_cast<const float4*>(
            &q[(size_t)(b * NNq + i0t + i) * DDm + h * DHh + d4]);
        *reinterpret_cast<float4*>(&Qs[i][d4]) = qv;
    }
#pragma unroll
    for (int r = 0; r < 4; ++r) {
        int idx = r * 256 + tid;
        int j = idx >> 3, d4 = (idx & 7) * 4;
        float4 kv = *reinterpret_cast<const float4*>(
            &k[(size_t)(b * NNq + j0t + j) * DDm + h * DHh + d4]);
        Kst[d4 + 0][j] = kv.x; Kst[d4 + 1][j] = kv.y;
        Kst[d4 + 2][j] = kv.z; Kst[d4 + 3][j] = kv.w;
    }
    __syncthreads();

    int tx = tid & 31, ty = tid >> 5;
    int i0 = ty * 4, j0 = tx * 4;
    float acc[4][4] = {};
#pragma unroll 8
    for (int d = 0; d < 32; ++d) {
        float4 kv = *reinterpret_cast<const float4*>(&Kst[d][j0]);
#pragma unroll
        for (int e = 0; e < 4; ++e) {
            float a = Qs[i0 + e][d];
            acc[e][0] = fmaf(a, kv.x, acc[e][0]);
            acc[e][1] = fmaf(a, kv.y, acc[e][1]);
            acc[e][2] = fmaf(a, kv.z, acc[e][2]);
            acc[e][3] = fmaf(a, kv.w, acc[e][3]);
        }
    }

    int plane = l * 8 + h;
    size_t pl = (size_t)NNq * NNq;
#pragma unroll
    for (int e = 0; e < 4; ++e) {
        int ig = i0t + i0 + e;
        int jg = j0t + j0;
        H4 g4 = *reinterpret_cast<const H4*>(
            &geo[(size_t)(plane * BB + b) * pl + (size_t)ig * NNq + jg]);
        int4 mv = *reinterpret_cast<const int4*>(&mask[(size_t)(b * NNq + ig) * NNq + jg]);
        float4 sv;
        sv.x = acc[e][0] * SCALE + __logf(__half2float(g4.a) + 1e-6f);
        sv.y = acc[e][1] * SCALE + __logf(__half2float(g4.b) + 1e-6f);
        sv.z = acc[e][2] * SCALE + __logf(__half2float(g4.c) + 1e-6f);
        sv.w = acc[e][3] * SCALE + __logf(__half2float(g4.d) + 1e-6f);
        if (mv.x == 0) sv.x = -1e9f;
        if (mv.y == 0) sv.y = -1e9f;
        if (mv.z == 0) sv.z = -1e9f;
        if (mv.w == 0) sv.w = -1e9f;
        *reinterpret_cast<float4*>(&S[((size_t)(b * HHh + h) * NNq + ig) * NNq + jg]) = sv;
    }
}

// ---------------------------------------------------------------- softmax (rows of 512)
__global__ __launch_bounds__(256) void k_softmax(float* __restrict__ S) {
    int row = blockIdx.x * 4 + (threadIdx.x >> 6);
    int lane = threadIdx.x & 63;
    float4* rp = reinterpret_cast<float4*>(S + (size_t)row * NNq);
    float4 v0 = rp[lane], v1 = rp[lane + 64];
    float mx = fmaxf(fmaxf(fmaxf(v0.x, v0.y), fmaxf(v0.z, v0.w)),
                     fmaxf(fmaxf(v1.x, v1.y), fmaxf(v1.z, v1.w)));
#pragma unroll
    for (int o = 32; o > 0; o >>= 1) mx = fmaxf(mx, __shfl_xor(mx, o, 64));
    v0.x = __expf(v0.x - mx); v0.y = __expf(v0.y - mx);
    v0.z = __expf(v0.z - mx); v0.w = __expf(v0.w - mx);
    v1.x = __expf(v1.x - mx); v1.y = __expf(v1.y - mx);
    v1.z = __expf(v1.z - mx); v1.w = __expf(v1.w - mx);
    float sum = v0.x + v0.y + v0.z + v0.w + v1.x + v1.y + v1.z + v1.w;
#pragma unroll
    for (int o = 32; o > 0; o >>= 1) sum += __shfl_xor(sum, o, 64);
    float inv = 1.0f / sum;
    v0.x *= inv; v0.y *= inv; v0.z *= inv; v0.w *= inv;
    v1.x *= inv; v1.y *= inv; v1.z *= inv; v1.w *= inv;
    rp[lane] = v0; rp[lane + 64] = v1;
}

// ---------------------------------------------------------------- PV
// y[b,i,h*32+d] = sum_j P[b,h,i,j] * v[b,j,h*32+d]. Block: (b,h) x i-tile 64.
__global__ __launch_bounds__(256) void k_pv(const float* __restrict__ P,
                                            const float* __restrict__ v,
                                            float* __restrict__ y) {
    int bh = blockIdx.y;
    int b = bh >> 3, h = bh & 7;
    int i0t = blockIdx.x * 64;
    __shared__ float Ps[64][65];
    __shared__ float Vs[64][36];
    int tid = threadIdx.x;
    int tx = tid & 7, ty = tid >> 3;
    int d4 = tx * 4, i0 = ty * 2;
    float acc[2][4] = {};

    for (int j0 = 0; j0 < NNq; j0 += 64) {
#pragma unroll
        for (int r = 0; r < 4; ++r) {
            int idx = r * 1024 + tid * 4;
            int i = idx >> 6, j4 = idx & 63;
            float4 p4 = *reinterpret_cast<const float4*>(
                &P[((size_t)(b * HHh + h) * NNq + i0t + i) * NNq + j0 + j4]);
            Ps[i][j4 + 0] = p4.x; Ps[i][j4 + 1] = p4.y;
            Ps[i][j4 + 2] = p4.z; Ps[i][j4 + 3] = p4.w;
        }
#pragma unroll
        for (int r = 0; r < 2; ++r) {
            int idx = r * 1024 + tid * 4;
            int j = idx >> 5, dd4 = idx & 31;
            float4 vv = *reinterpret_cast<const float4*>(
                &v[(size_t)(b * NNq + j0 + j) * DDm + h * DHh + dd4]);
            *reinterpret_cast<float4*>(&Vs[j][dd4]) = vv;
        }
        __syncthreads();
#pragma unroll 8
        for (int j = 0; j < 64; ++j) {
            float4 vv = *reinterpret_cast<const float4*>(&Vs[j][d4]);
            float a0 = Ps[i0][j], a1 = Ps[i0 + 1][j];
            acc[0][0] = fmaf(a0, vv.x, acc[0][0]);
            acc[0][1] = fmaf(a0, vv.y, acc[0][1]);
            acc[0][2] = fmaf(a0, vv.z, acc[0][2]);
            acc[0][3] = fmaf(a0, vv.w, acc[0][3]);
            acc[1][0] = fmaf(a1, vv.x, acc[1][0]);
            acc[1][1] = fmaf(a1, vv.y, acc[1][1]);
            acc[1][2] = fmaf(a1, vv.z, acc[1][2]);
            acc[1][3] = fmaf(a1, vv.w, acc[1][3]);
        }
        __syncthreads();
    }
#pragma unroll
    for (int e = 0; e < 2; ++e) {
        *reinterpret_cast<float4*>(
            &y[(size_t)(b * NNq + i0t + i0 + e) * DDm + h * DHh + d4]) =
            make_float4(acc[e][0], acc[e][1], acc[e][2], acc[e][3]);
    }
}

// ---------------------------------------------------------------- launch
extern "C" void kernel_launch(void* const* d_in, const int* in_sizes, int n_in,
                              void* d_out, int out_size, void* d_ws, size_t ws_size,
                              hipStream_t stream) {
    const float* boxes    = (const float*)d_in[0];
    const float* features = (const float*)d_in[1];
    const int*   mask     = (const int*)d_in[2];
    const float* Wq = (const float*)d_in[3];
    const float* bq = (const float*)d_in[4];
    const float* Wk = (const float*)d_in[5];
    const float* bk = (const float*)d_in[6];
    const float* Wv = (const float*)d_in[7];
    const float* bv = (const float*)d_in[8];
    const float* Wo = (const float*)d_in[9];
    const float* bo = (const float*)d_in[10];
    const float* Wg = (const float*)d_in[11];
    const float* bg = (const float*)d_in[12];
    const float* dv = (const float*)d_in[13];

    char* ws = (char*)d_ws;
    // workspace layout (bytes)
    float*  boxp = (float*)(ws);                              //    16,384
    __half* geo  = (__half*)(ws + 16384);                     // 25,165,824
    float*  qb   = (float*)(ws + 25182208);                   //  1,048,576
    float*  kb   = (float*)(ws + 26230784);                   //  1,048,576
    float*  vb   = (float*)(ws + 27279360);                   //  1,048,576
    float*  yb   = (float*)(ws + 28327936);                   //  1,048,576
    float*  Sb   = (float*)(ws + 29376512);                   // 16,777,216  -> total ~46.2 MB
    float*  x    = (float*)d_out;

    hipMemcpyAsync(x, features, (size_t)BB * NNq * DDm * sizeof(float),
                   hipMemcpyDeviceToDevice, stream);
    k_boxprep<<<dim3((BB * NNq + 255) / 256), dim3(256), 0, stream>>>(boxes, boxp);
    k_geo<<<dim3(2048), dim3(256), 0, stream>>>(boxp, Wg, bg, dv, geo);

    for (int l = 0; l < LLn; ++l) {
        const float* Wq_l = Wq + (size_t)l * DDm * DDm;
        const float* Wk_l = Wk + (size_t)l * DDm * DDm;
        const float* Wv_l = Wv + (size_t)l * DDm * DDm;
        const float* Wo_l = Wo + (size_t)l * DDm * DDm;
        const float* bq_l = bq + (size_t)l * DDm;
        const float* bk_l = bk + (size_t)l * DDm;
        const float* bv_l = bv + (size_t)l * DDm;
        const float* bo_l = bo + (size_t)l * DDm;

        k_gemm<<<dim3(16, 4, 3), dim3(256), 0, stream>>>(
            x, Wq_l, Wk_l, Wv_l, bq_l, bk_l, bv_l, qb, kb, vb, nullptr);
        k_score<<<dim3(4, 16, 16), dim3(256), 0, stream>>>(qb, kb, geo, mask, Sb, l);
        k_softmax<<<dim3(BB * HHh * NNq / 4), dim3(256), 0, stream>>>(Sb);
        k_pv<<<dim3(8, 16), dim3(256), 0, stream>>>(Sb, vb, yb);
        k_gemm<<<dim3(16, 4, 1), dim3(256), 0, stream>>>(
            yb, Wo_l, Wo_l, Wo_l, bo_l, bo_l, bo_l, x, x, x, x);
    }
}

// Round 5
// 257.847 us; speedup vs baseline: 1.2906x; 1.1647x over previous
//
#include <hip/hip_runtime.h>
#include <hip/hip_fp16.h>

// Problem constants (from reference): B=2, N=512, D=256, H=8, L=3
#define BB 2
#define NNq 512
#define DDm 256
#define HHh 8
#define DHh 32
#define LLn 3

static constexpr float EPSF   = 1e-4f;
static constexpr float INV2PI = 0.15915494309189535f;   // 1/(2*pi)
static constexpr float SCALE  = 0.17677669529663687f;   // 1/sqrt(32)

#if __has_builtin(__builtin_amdgcn_fractf)
#define FRACTF(x) __builtin_amdgcn_fractf(x)
#else
#define FRACTF(x) ((x) - floorf(x))
#endif
#if __has_builtin(__builtin_amdgcn_sinf)
#define SINR(x) __builtin_amdgcn_sinf(x)   // sin(2*pi*x), x in revolutions
#define COSR(x) __builtin_amdgcn_cosf(x)
#else
#define SINR(x) __sinf((x) * 6.2831853071795865f)
#define COSR(x) __cosf((x) * 6.2831853071795865f)
#endif

struct __align__(8) H4 { __half a, b, c, d; };

typedef _Float16 f16x8 __attribute__((ext_vector_type(8)));
typedef float    f32x4 __attribute__((ext_vector_type(4)));

// ---------------------------------------------------------------- boxprep
__global__ __launch_bounds__(256) void k_boxprep(const float* __restrict__ boxes,
                                                 float* __restrict__ boxp) {
    int idx = blockIdx.x * 256 + threadIdx.x;
    if (idx >= BB * NNq) return;
    float4 bx = reinterpret_cast<const float4*>(boxes)[idx];
    float cx = 0.5f * (bx.x + bx.z), cy = 0.5f * (bx.y + bx.w);
    float w = fmaxf(bx.z - bx.x, EPSF), h = fmaxf(bx.w - bx.y, EPSF);
    reinterpret_cast<float4*>(boxp)[idx] = make_float4(cx, cy, w, h);
}

// ---------------------------------------------------------------- geo (MFMA, fp16)
// geo[t][b][i][j] = relu(emb(b,i,j) @ Wg[:,t] + bg[t]),  t = l*8 + h  (24 outputs).
// MFMA core unchanged from round 4 (verified). Round-5 change: C results are
// staged into a per-wave LDS buffer [24 t][64 j] and written out as 24
// contiguous 128-byte rows (full-line stores). Previously each lane scattered
// 2-byte stores across 16 t-planes -> L2 read-modify-write (FETCH_SIZE=247MB
// on ~250KB of inputs, WRITE_SIZE=2x ideal, k_geo 56us store-bound).
__global__ __launch_bounds__(256) void k_geo(const float* __restrict__ boxp,
                                             const float* __restrict__ Wg,
                                             const float* __restrict__ bg,
                                             const float* __restrict__ divm,
                                             __half* __restrict__ geo) {
    __shared__ _Float16 WgT[32 * 256];   // [n][k] fp16, k XOR-swizzled by (n&7)<<3
    __shared__ __half obuf[4][24][68];   // per-wave: [t][j-within-64], pad 68
    const int tid = threadIdx.x;
    // stage Wg -> WgT (fp16, transposed, swizzled); n>=24 zero-padded
    for (int idx = tid; idx < 32 * 256; idx += 256) {
        int n = idx >> 8, k = idx & 255;
        float w = (n < 24) ? Wg[(size_t)(n >> 3) * 2048 + (size_t)k * 8 + (n & 7)] : 0.f;
        WgT[n * 256 + (k ^ ((n & 7) << 3))] = (_Float16)w;
    }
    __syncthreads();

    const int lane = tid & 63;
    const int wid  = tid >> 6;
    const int ln15 = lane & 15;
    const int kgrp = lane >> 4;          // 0..3

    // per-lane inv divisors for its 8 f-slots (f0 = kgrp*8)
    float invd[8];
    {
        const float4* dv4 = reinterpret_cast<const float4*>(divm);
        float4 da = dv4[kgrp * 2], db = dv4[kgrp * 2 + 1];
        invd[0] = INV2PI / da.x; invd[1] = INV2PI / da.y;
        invd[2] = INV2PI / da.z; invd[3] = INV2PI / da.w;
        invd[4] = INV2PI / db.x; invd[5] = INV2PI / db.y;
        invd[6] = INV2PI / db.z; invd[7] = INV2PI / db.w;
    }
    const int n0 = ln15;            // output col, tile 0 (always < 24)
    const int n1 = 16 + ln15;       // output col, tile 1 (valid if < 24)
    const float bg0 = bg[n0];
    const float bg1 = (n1 < 24) ? bg[n1] : 0.f;

    // swizzle involution split into disjoint bit-fields (round-4 fix)
    const int mask  = (ln15 & 7) << 3;          // bits 3..5
    const int flip5 = mask & 32;                // bit 5 -> flips kc low bit
    const int kb    = (kgrp << 3) ^ (mask & 24);
    const int base0 = n0 * 256 + kb;
    const int base1 = n1 * 256 + kb;

    const float4* boxp4 = reinterpret_cast<const float4*>(boxp);
    const size_t plane = (size_t)NNq * NNq;

    const int base4 = (blockIdx.x * 4 + wid) * 4;   // 4 consecutive slabs per wave
#pragma unroll
    for (int it = 0; it < 4; ++it) {
        const int slab = base4 + it;                // 0..32767
        const int p0 = slab << 4;
        const int b  = p0 >> 18;
        const int rem = p0 & (NNq * NNq - 1);
        const int i  = rem >> 9;
        const int j0 = rem & (NNq - 1);

        float4 bi = boxp4[b * NNq + i];
        float4 bj = boxp4[b * NNq + j0 + ln15];     // A-row ln15's key box
        float rel[4];
        rel[0] = __logf(fabsf(bj.x - bi.x) / bj.z + EPSF);
        rel[1] = __logf(fabsf(bj.y - bi.y) / bj.w + EPSF);
        rel[2] = __logf(bi.z / bj.z + EPSF);
        rel[3] = __logf(bi.w / bj.w + EPSF);

        f32x4 acc0 = {0.f, 0.f, 0.f, 0.f};
        f32x4 acc1 = {0.f, 0.f, 0.f, 0.f};

#pragma unroll
        for (int kc = 0; kc < 8; ++kc) {
            const float rc = rel[kc >> 1];
            f16x8 af;
#pragma unroll
            for (int j = 0; j < 8; ++j) {
                float rv = FRACTF(rc * invd[j]);
                af[j] = (_Float16)((kc & 1) ? COSR(rv) : SINR(rv));
            }
            const int koff = (kc * 32) ^ flip5;     // swizzle-correct chunk offset
            f16x8 bf0 = *reinterpret_cast<const f16x8*>(&WgT[base0 + koff]);
            f16x8 bf1 = *reinterpret_cast<const f16x8*>(&WgT[base1 + koff]);
            acc0 = __builtin_amdgcn_mfma_f32_16x16x32_f16(af, bf0, acc0, 0, 0, 0);
            acc1 = __builtin_amdgcn_mfma_f32_16x16x32_f16(af, bf1, acc1, 0, 0, 0);
        }

#pragma unroll
        for (int r = 0; r < 4; ++r) {
            const int m = it * 16 + (kgrp << 2) + r;    // j within the 64-run
            float g0 = fmaxf(acc0[r] + bg0, 0.f);
            obuf[wid][n0][m] = __float2half(g0);
            if (n1 < 24) {
                float g1 = fmaxf(acc1[r] + bg1, 0.f);
                obuf[wid][n1][m] = __float2half(g1);
            }
        }
    }
    __syncthreads();   // also orders LDS writes before cross-lane reads

    // coalesced write-out: 24 rows of 64 contiguous halfs (128B each)
    const int b_  = base4 >> 14;
    const int i_  = (base4 >> 5) & (NNq - 1);
    const int j0b = (base4 & 31) << 4;
    size_t obase = (size_t)b_ * plane + (size_t)i_ * NNq + j0b + lane;
#pragma unroll
    for (int t = 0; t < 24; ++t) {
        geo[obase + (size_t)t * (BB * plane)] = obuf[wid][t][lane];
    }
}

// ---------------------------------------------------------------- GEMM
// C[z] = relu(A @ W[z] + bias[z]) (+ resid). M x 256 @ 256 x 256.
// Tile 64x64, BK=16, 256 threads, 4x4 per thread.
__global__ __launch_bounds__(256) void k_gemm(const float* __restrict__ A,
        const float* __restrict__ W0, const float* __restrict__ W1, const float* __restrict__ W2,
        const float* __restrict__ b0, const float* __restrict__ b1, const float* __restrict__ b2,
        float* __restrict__ C0, float* __restrict__ C1, float* __restrict__ C2,
        const float* __restrict__ resid) {
    const float* W   = (blockIdx.z == 0) ? W0 : (blockIdx.z == 1) ? W1 : W2;
    const float* bia = (blockIdx.z == 0) ? b0 : (blockIdx.z == 1) ? b1 : b2;
    float*       C   = (blockIdx.z == 0) ? C0 : (blockIdx.z == 1) ? C1 : C2;

    __shared__ float As[64][17];
    __shared__ float Bs[16][64];
    int tid = threadIdx.x;
    int tx = tid & 15, ty = tid >> 4;
    int m0 = blockIdx.x * 64, n0 = blockIdx.y * 64;
    float acc[4][4] = {};

    int arow = tid >> 2, ac4 = (tid & 3) * 4;
    int bk = tid >> 4, bn4 = (tid & 15) * 4;

    for (int k0 = 0; k0 < 256; k0 += 16) {
        float4 av = *reinterpret_cast<const float4*>(&A[(size_t)(m0 + arow) * 256 + k0 + ac4]);
        As[arow][ac4 + 0] = av.x; As[arow][ac4 + 1] = av.y;
        As[arow][ac4 + 2] = av.z; As[arow][ac4 + 3] = av.w;
        *reinterpret_cast<float4*>(&Bs[bk][bn4]) =
            *reinterpret_cast<const float4*>(&W[(size_t)(k0 + bk) * 256 + n0 + bn4]);
        __syncthreads();
#pragma unroll
        for (int k = 0; k < 16; ++k) {
            float4 bv = *reinterpret_cast<const float4*>(&Bs[k][tx * 4]);
#pragma unroll
            for (int e = 0; e < 4; ++e) {
                float a = As[ty * 4 + e][k];
                acc[e][0] = fmaf(a, bv.x, acc[e][0]);
                acc[e][1] = fmaf(a, bv.y, acc[e][1]);
                acc[e][2] = fmaf(a, bv.z, acc[e][2]);
                acc[e][3] = fmaf(a, bv.w, acc[e][3]);
            }
        }
        __syncthreads();
    }

    float4 bias4 = *reinterpret_cast<const float4*>(&bia[n0 + tx * 4]);
#pragma unroll
    for (int e = 0; e < 4; ++e) {
        int row = m0 + ty * 4 + e;
        float4 o;
        o.x = fmaxf(acc[e][0] + bias4.x, 0.f);
        o.y = fmaxf(acc[e][1] + bias4.y, 0.f);
        o.z = fmaxf(acc[e][2] + bias4.z, 0.f);
        o.w = fmaxf(acc[e][3] + bias4.w, 0.f);
        if (resid) {
            float4 rv = *reinterpret_cast<const float4*>(&resid[(size_t)row * 256 + n0 + tx * 4]);
            o.x += rv.x; o.y += rv.y; o.z += rv.z; o.w += rv.w;
        }
        *reinterpret_cast<float4*>(&C[(size_t)row * 256 + n0 + tx * 4]) = o;
    }
}

// ---------------------------------------------------------------- fused attention
// One block = (b,h) x 32 q-rows. Streams K/V in j-blocks of 128 through LDS,
// computes S = qk*SCALE + log(geo+1e-6) (masked), online softmax, accumulates
// O = P@V. Replaces k_score + k_softmax + k_pv (kills the 16.8MB S buffer).
__global__ __launch_bounds__(256) void k_attn(const float* __restrict__ q,
                                              const float* __restrict__ kk,
                                              const float* __restrict__ vv,
                                              const __half* __restrict__ geo,
                                              const int* __restrict__ mask,
                                              float* __restrict__ y, int l) {
    const int bh = blockIdx.y;
    const int b = bh >> 3, h = bh & 7;
    const int i0t = blockIdx.x * 32;

    __shared__ float Qs[32][36];
    __shared__ float Kst[32][132];   // [d][j] transposed
    __shared__ float Vs[128][36];
    __shared__ float Ps[32][132];
    __shared__ float rowc[32], rowl[32];

    const int tid = threadIdx.x;
    // S-compute layout (k_score-proven): 4 rows x 4 j per thread
    const int tx = tid & 31, ty = tid >> 5;
    const int si0 = ty * 4, sj0 = tx * 4;
    // PV layout: 1 row x 4 d per thread
    const int prow = tid >> 3, pd4 = (tid & 7) * 4;

    {   // load Q tile
        int i = tid >> 3, d4 = (tid & 7) * 4;
        *reinterpret_cast<float4*>(&Qs[i][d4]) = *reinterpret_cast<const float4*>(
            &q[(size_t)(b * NNq + i0t + i) * DDm + h * DHh + d4]);
    }

    float m_r[4], l_r[4];
#pragma unroll
    for (int e = 0; e < 4; ++e) { m_r[e] = -3.0e38f; l_r[e] = 0.f; }
    float4 oacc = make_float4(0.f, 0.f, 0.f, 0.f);

    const size_t plane = (size_t)NNq * NNq;
    const size_t geo_base = (size_t)((l * 8 + h) * BB + b) * plane;

    for (int jb = 0; jb < 4; ++jb) {
        const int j0t = jb * 128;
        __syncthreads();   // previous PV reads done before re-staging
#pragma unroll
        for (int r = 0; r < 4; ++r) {   // K transposed
            int idx = r * 256 + tid;
            int j = idx >> 3, d4 = (idx & 7) * 4;
            float4 kv = *reinterpret_cast<const float4*>(
                &kk[(size_t)(b * NNq + j0t + j) * DDm + h * DHh + d4]);
            Kst[d4 + 0][j] = kv.x; Kst[d4 + 1][j] = kv.y;
            Kst[d4 + 2][j] = kv.z; Kst[d4 + 3][j] = kv.w;
        }
#pragma unroll
        for (int r = 0; r < 4; ++r) {   // V
            int idx = r * 256 + tid;
            int j = idx >> 3, d4 = (idx & 7) * 4;
            *reinterpret_cast<float4*>(&Vs[j][d4]) = *reinterpret_cast<const float4*>(
                &vv[(size_t)(b * NNq + j0t + j) * DDm + h * DHh + d4]);
        }
        __syncthreads();

        // S tile 32x128
        float acc[4][4] = {};
#pragma unroll 8
        for (int d = 0; d < 32; ++d) {
            float4 kv = *reinterpret_cast<const float4*>(&Kst[d][sj0]);
#pragma unroll
            for (int e = 0; e < 4; ++e) {
                float a = Qs[si0 + e][d];
                acc[e][0] = fmaf(a, kv.x, acc[e][0]);
                acc[e][1] = fmaf(a, kv.y, acc[e][1]);
                acc[e][2] = fmaf(a, kv.z, acc[e][2]);
                acc[e][3] = fmaf(a, kv.w, acc[e][3]);
            }
        }

        // epilogue: geo/mask, online-softmax stats over tx (32 lanes, same ty)
#pragma unroll
        for (int e = 0; e < 4; ++e) {
            int ig = i0t + si0 + e;
            int jg = j0t + sj0;
            H4 g4 = *reinterpret_cast<const H4*>(&geo[geo_base + (size_t)ig * NNq + jg]);
            int4 mv = *reinterpret_cast<const int4*>(&mask[(size_t)(b * NNq + ig) * NNq + jg]);
            float4 sv;
            sv.x = acc[e][0] * SCALE + __logf(__half2float(g4.a) + 1e-6f);
            sv.y = acc[e][1] * SCALE + __logf(__half2float(g4.b) + 1e-6f);
            sv.z = acc[e][2] * SCALE + __logf(__half2float(g4.c) + 1e-6f);
            sv.w = acc[e][3] * SCALE + __logf(__half2float(g4.d) + 1e-6f);
            if (mv.x == 0) sv.x = -1e9f;
            if (mv.y == 0) sv.y = -1e9f;
            if (mv.z == 0) sv.z = -1e9f;
            if (mv.w == 0) sv.w = -1e9f;

            float mx = fmaxf(fmaxf(sv.x, sv.y), fmaxf(sv.z, sv.w));
#pragma unroll
            for (int o = 16; o > 0; o >>= 1) mx = fmaxf(mx, __shfl_xor(mx, o, 32));
            float mnew = fmaxf(m_r[e], mx);
            float c = __expf(m_r[e] - mnew);
            sv.x = __expf(sv.x - mnew); sv.y = __expf(sv.y - mnew);
            sv.z = __expf(sv.z - mnew); sv.w = __expf(sv.w - mnew);
            float s4 = sv.x + sv.y + sv.z + sv.w;
#pragma unroll
            for (int o = 16; o > 0; o >>= 1) s4 += __shfl_xor(s4, o, 32);
            l_r[e] = l_r[e] * c + s4;
            m_r[e] = mnew;
            *reinterpret_cast<float4*>(&Ps[si0 + e][sj0]) = sv;
            if (tx == 0) rowc[si0 + e] = c;
        }
        __syncthreads();

        // PV accumulate (rescale by this tile's correction factor)
        float cr = rowc[prow];
        oacc.x *= cr; oacc.y *= cr; oacc.z *= cr; oacc.w *= cr;
#pragma unroll 8
        for (int j = 0; j < 128; j += 4) {
            float4 p4 = *reinterpret_cast<const float4*>(&Ps[prow][j]);
            float4 v0 = *reinterpret_cast<const float4*>(&Vs[j + 0][pd4]);
            float4 v1 = *reinterpret_cast<const float4*>(&Vs[j + 1][pd4]);
            float4 v2 = *reinterpret_cast<const float4*>(&Vs[j + 2][pd4]);
            float4 v3 = *reinterpret_cast<const float4*>(&Vs[j + 3][pd4]);
            oacc.x = fmaf(p4.x, v0.x, oacc.x); oacc.y = fmaf(p4.x, v0.y, oacc.y);
            oacc.z = fmaf(p4.x, v0.z, oacc.z); oacc.w = fmaf(p4.x, v0.w, oacc.w);
            oacc.x = fmaf(p4.y, v1.x, oacc.x); oacc.y = fmaf(p4.y, v1.y, oacc.y);
            oacc.z = fmaf(p4.y, v1.z, oacc.z); oacc.w = fmaf(p4.y, v1.w, oacc.w);
            oacc.x = fmaf(p4.z, v2.x, oacc.x); oacc.y = fmaf(p4.z, v2.y, oacc.y);
            oacc.z = fmaf(p4.z, v2.z, oacc.z); oacc.w = fmaf(p4.z, v2.w, oacc.w);
            oacc.x = fmaf(p4.w, v3.x, oacc.x); oacc.y = fmaf(p4.w, v3.y, oacc.y);
            oacc.z = fmaf(p4.w, v3.z, oacc.z); oacc.w = fmaf(p4.w, v3.w, oacc.w);
        }
    }

    if (tx == 0) {
#pragma unroll
        for (int e = 0; e < 4; ++e) rowl[si0 + e] = l_r[e];
    }
    __syncthreads();
    float inv = 1.0f / rowl[prow];
    oacc.x *= inv; oacc.y *= inv; oacc.z *= inv; oacc.w *= inv;
    *reinterpret_cast<float4*>(&y[(size_t)(b * NNq + i0t + prow) * DDm + h * DHh + pd4]) = oacc;
}

// ---------------------------------------------------------------- launch
extern "C" void kernel_launch(void* const* d_in, const int* in_sizes, int n_in,
                              void* d_out, int out_size, void* d_ws, size_t ws_size,
                              hipStream_t stream) {
    const float* boxes    = (const float*)d_in[0];
    const float* features = (const float*)d_in[1];
    const int*   mask     = (const int*)d_in[2];
    const float* Wq = (const float*)d_in[3];
    const float* bq = (const float*)d_in[4];
    const float* Wk = (const float*)d_in[5];
    const float* bk = (const float*)d_in[6];
    const float* Wv = (const float*)d_in[7];
    const float* bv = (const float*)d_in[8];
    const float* Wo = (const float*)d_in[9];
    const float* bo = (const float*)d_in[10];
    const float* Wg = (const float*)d_in[11];
    const float* bg = (const float*)d_in[12];
    const float* dv = (const float*)d_in[13];

    char* ws = (char*)d_ws;
    // workspace layout (bytes)
    float*  boxp = (float*)(ws);                              //    16,384
    __half* geo  = (__half*)(ws + 16384);                     // 25,165,824
    float*  qb   = (float*)(ws + 25182208);                   //  1,048,576
    float*  kb   = (float*)(ws + 26230784);                   //  1,048,576
    float*  vb   = (float*)(ws + 27279360);                   //  1,048,576
    float*  yb   = (float*)(ws + 28327936);                   //  1,048,576  -> ~29.4 MB
    float*  x    = (float*)d_out;

    hipMemcpyAsync(x, features, (size_t)BB * NNq * DDm * sizeof(float),
                   hipMemcpyDeviceToDevice, stream);
    k_boxprep<<<dim3((BB * NNq + 255) / 256), dim3(256), 0, stream>>>(boxes, boxp);
    k_geo<<<dim3(2048), dim3(256), 0, stream>>>(boxp, Wg, bg, dv, geo);

    for (int l = 0; l < LLn; ++l) {
        const float* Wq_l = Wq + (size_t)l * DDm * DDm;
        const float* Wk_l = Wk + (size_t)l * DDm * DDm;
        const float* Wv_l = Wv + (size_t)l * DDm * DDm;
        const float* Wo_l = Wo + (size_t)l * DDm * DDm;
        const float* bq_l = bq + (size_t)l * DDm;
        const float* bk_l = bk + (size_t)l * DDm;
        const float* bv_l = bv + (size_t)l * DDm;
        const float* bo_l = bo + (size_t)l * DDm;

        k_gemm<<<dim3(16, 4, 3), dim3(256), 0, stream>>>(
            x, Wq_l, Wk_l, Wv_l, bq_l, bk_l, bv_l, qb, kb, vb, nullptr);
        k_attn<<<dim3(16, 16), dim3(256), 0, stream>>>(qb, kb, vb, geo, mask, yb, l);
        k_gemm<<<dim3(16, 4, 1), dim3(256), 0, stream>>>(
            yb, Wo_l, Wo_l, Wo_l, bo_l, bo_l, bo_l, x, x, x, x);
    }
}

// Round 6
// 233.553 us; speedup vs baseline: 1.4248x; 1.1040x over previous
//
#include <hip/hip_runtime.h>
#include <hip/hip_fp16.h>

// Problem constants (from reference): B=2, N=512, D=256, H=8, L=3
#define BB 2
#define NNq 512
#define DDm 256
#define HHh 8
#define DHh 32
#define LLn 3

static constexpr float EPSF   = 1e-4f;
static constexpr float INV2PI = 0.15915494309189535f;   // 1/(2*pi)
static constexpr float SCALE  = 0.17677669529663687f;   // 1/sqrt(32)

#if __has_builtin(__builtin_amdgcn_fractf)
#define FRACTF(x) __builtin_amdgcn_fractf(x)
#else
#define FRACTF(x) ((x) - floorf(x))
#endif
#if __has_builtin(__builtin_amdgcn_sinf)
#define SINR(x) __builtin_amdgcn_sinf(x)   // sin(2*pi*x), x in revolutions
#define COSR(x) __builtin_amdgcn_cosf(x)
#else
#define SINR(x) __sinf((x) * 6.2831853071795865f)
#define COSR(x) __cosf((x) * 6.2831853071795865f)
#endif

struct __align__(8) H4 { __half a, b, c, d; };

typedef _Float16 f16x8 __attribute__((ext_vector_type(8)));
typedef float    f32x4 __attribute__((ext_vector_type(4)));

// ---------------------------------------------------------------- boxprep
__global__ __launch_bounds__(256) void k_boxprep(const float* __restrict__ boxes,
                                                 float* __restrict__ boxp) {
    int idx = blockIdx.x * 256 + threadIdx.x;
    if (idx >= BB * NNq) return;
    float4 bx = reinterpret_cast<const float4*>(boxes)[idx];
    float cx = 0.5f * (bx.x + bx.z), cy = 0.5f * (bx.y + bx.w);
    float w = fmaxf(bx.z - bx.x, EPSF), h = fmaxf(bx.w - bx.y, EPSF);
    reinterpret_cast<float4*>(boxp)[idx] = make_float4(cx, cy, w, h);
}

// ---------------------------------------------------------------- geo (MFMA, fp16)
// geo[t][b][i][j] = relu(emb(b,i,j) @ Wg[:,t] + bg[t]),  t = l*8 + h  (24 outputs).
// Round-6 tweak: each angle's mul+fract computed once, feeding both the sin-
// and cos-chunk MFMAs (was recomputed per chunk).
__global__ __launch_bounds__(256) void k_geo(const float* __restrict__ boxp,
                                             const float* __restrict__ Wg,
                                             const float* __restrict__ bg,
                                             const float* __restrict__ divm,
                                             __half* __restrict__ geo) {
    __shared__ _Float16 WgT[32 * 256];   // [n][k] fp16, k XOR-swizzled by (n&7)<<3
    __shared__ __half obuf[4][24][68];   // per-wave: [t][j-within-64], pad 68
    const int tid = threadIdx.x;
    for (int idx = tid; idx < 32 * 256; idx += 256) {
        int n = idx >> 8, k = idx & 255;
        float w = (n < 24) ? Wg[(size_t)(n >> 3) * 2048 + (size_t)k * 8 + (n & 7)] : 0.f;
        WgT[n * 256 + (k ^ ((n & 7) << 3))] = (_Float16)w;
    }
    __syncthreads();

    const int lane = tid & 63;
    const int wid  = tid >> 6;
    const int ln15 = lane & 15;
    const int kgrp = lane >> 4;          // 0..3

    float invd[8];
    {
        const float4* dv4 = reinterpret_cast<const float4*>(divm);
        float4 da = dv4[kgrp * 2], db = dv4[kgrp * 2 + 1];
        invd[0] = INV2PI / da.x; invd[1] = INV2PI / da.y;
        invd[2] = INV2PI / da.z; invd[3] = INV2PI / da.w;
        invd[4] = INV2PI / db.x; invd[5] = INV2PI / db.y;
        invd[6] = INV2PI / db.z; invd[7] = INV2PI / db.w;
    }
    const int n0 = ln15;            // output col, tile 0 (always < 24)
    const int n1 = 16 + ln15;       // output col, tile 1 (valid if < 24)
    const float bg0 = bg[n0];
    const float bg1 = (n1 < 24) ? bg[n1] : 0.f;

    // swizzle involution split into disjoint bit-fields (round-4 fix)
    const int mask  = (ln15 & 7) << 3;          // bits 3..5
    const int flip5 = mask & 32;                // bit 5 -> flips kc low bit
    const int kb    = (kgrp << 3) ^ (mask & 24);
    const int base0 = n0 * 256 + kb;
    const int base1 = n1 * 256 + kb;

    const float4* boxp4 = reinterpret_cast<const float4*>(boxp);
    const size_t plane = (size_t)NNq * NNq;

    const int base4 = (blockIdx.x * 4 + wid) * 4;   // 4 consecutive slabs per wave
#pragma unroll
    for (int it = 0; it < 4; ++it) {
        const int slab = base4 + it;
        const int p0 = slab << 4;
        const int b  = p0 >> 18;
        const int rem = p0 & (NNq * NNq - 1);
        const int i  = rem >> 9;
        const int j0 = rem & (NNq - 1);

        float4 bi = boxp4[b * NNq + i];
        float4 bj = boxp4[b * NNq + j0 + ln15];
        float rel[4];
        rel[0] = __logf(fabsf(bj.x - bi.x) / bj.z + EPSF);
        rel[1] = __logf(fabsf(bj.y - bi.y) / bj.w + EPSF);
        rel[2] = __logf(bi.z / bj.z + EPSF);
        rel[3] = __logf(bi.w / bj.w + EPSF);

        f32x4 acc0 = {0.f, 0.f, 0.f, 0.f};
        f32x4 acc1 = {0.f, 0.f, 0.f, 0.f};

#pragma unroll
        for (int kc2 = 0; kc2 < 4; ++kc2) {
            const float rc = rel[kc2];
            f16x8 afs, afc;
#pragma unroll
            for (int j = 0; j < 8; ++j) {
                float rv = FRACTF(rc * invd[j]);
                afs[j] = (_Float16)SINR(rv);
                afc[j] = (_Float16)COSR(rv);
            }
            const int koffS = ((2 * kc2) * 32) ^ flip5;
            const int koffC = ((2 * kc2 + 1) * 32) ^ flip5;
            f16x8 b0s = *reinterpret_cast<const f16x8*>(&WgT[base0 + koffS]);
            f16x8 b0c = *reinterpret_cast<const f16x8*>(&WgT[base0 + koffC]);
            f16x8 b1s = *reinterpret_cast<const f16x8*>(&WgT[base1 + koffS]);
            f16x8 b1c = *reinterpret_cast<const f16x8*>(&WgT[base1 + koffC]);
            acc0 = __builtin_amdgcn_mfma_f32_16x16x32_f16(afs, b0s, acc0, 0, 0, 0);
            acc0 = __builtin_amdgcn_mfma_f32_16x16x32_f16(afc, b0c, acc0, 0, 0, 0);
            acc1 = __builtin_amdgcn_mfma_f32_16x16x32_f16(afs, b1s, acc1, 0, 0, 0);
            acc1 = __builtin_amdgcn_mfma_f32_16x16x32_f16(afc, b1c, acc1, 0, 0, 0);
        }

#pragma unroll
        for (int r = 0; r < 4; ++r) {
            const int m = it * 16 + (kgrp << 2) + r;    // j within the 64-run
            float g0 = fmaxf(acc0[r] + bg0, 0.f);
            obuf[wid][n0][m] = __float2half(g0);
            if (n1 < 24) {
                float g1 = fmaxf(acc1[r] + bg1, 0.f);
                obuf[wid][n1][m] = __float2half(g1);
            }
        }
    }
    __syncthreads();

    // coalesced write-out: 24 rows of 64 contiguous halfs (128B each)
    const int b_  = base4 >> 14;
    const int i_  = (base4 >> 5) & (NNq - 1);
    const int j0b = (base4 & 31) << 4;
    size_t obase = (size_t)b_ * plane + (size_t)i_ * NNq + j0b + lane;
#pragma unroll
    for (int t = 0; t < 24; ++t) {
        geo[obase + (size_t)t * (BB * plane)] = obuf[wid][t][lane];
    }
}

// ---------------------------------------------------------------- GEMM (MFMA fp16)
// C[z] = relu(A @ W[z] + bias[z]) (+ resid). M x 256 @ 256 x 256, fp32 I/O,
// fp16 MFMA with fp32 accum. Block = 256 thr (4 waves), tile 64(M) x 64(N),
// whole K=256 staged to LDS. Fragment recipe identical to verified k_geo:
// lane m/n = lane&15, k = kc*32 + (lane>>4)*8 + j on BOTH operands;
// C/D col=lane&15 (N), row=(lane>>4)*4+reg (M). Rows padded to 264 halfs
// (+16B) -> 2-way (free) bank aliasing on ds_read_b128, no XOR swizzle.
#define LDP 264
__global__ __launch_bounds__(256) void k_gemm_mfma(const float* __restrict__ A,
        const float* __restrict__ W0, const float* __restrict__ W1, const float* __restrict__ W2,
        const float* __restrict__ b0, const float* __restrict__ b1, const float* __restrict__ b2,
        float* __restrict__ C0, float* __restrict__ C1, float* __restrict__ C2,
        const float* __restrict__ resid) {
    const float* W   = (blockIdx.z == 0) ? W0 : (blockIdx.z == 1) ? W1 : W2;
    const float* bia = (blockIdx.z == 0) ? b0 : (blockIdx.z == 1) ? b1 : b2;
    float*       C   = (blockIdx.z == 0) ? C0 : (blockIdx.z == 1) ? C1 : C2;

    __shared__ _Float16 As[64 * LDP];   // [m][k] fp16, padded
    __shared__ _Float16 Ws[64 * LDP];   // [n][k] fp16 (W transposed), padded

    const int tid = threadIdx.x;
    const int m0 = blockIdx.x * 64, n0 = blockIdx.y * 64;

    // stage A: 64 rows x 256 k, fp32 -> fp16
    for (int u = tid; u < 64 * 64; u += 256) {          // u = float4 units
        int m = u >> 6, k4 = (u & 63) * 4;
        float4 av = *reinterpret_cast<const float4*>(&A[(size_t)(m0 + m) * 256 + k4]);
        _Float16* dst = &As[m * LDP + k4];
        dst[0] = (_Float16)av.x; dst[1] = (_Float16)av.y;
        dst[2] = (_Float16)av.z; dst[3] = (_Float16)av.w;
    }
    // stage W transposed: Ws[n][k] = W[k][n0+n]
    for (int u = tid; u < 64 * 64; u += 256) {          // n = u&63, k4 = (u>>6)*4
        int n = u & 63, k4 = (u >> 6) * 4;
#pragma unroll
        for (int e = 0; e < 4; ++e)
            Ws[n * LDP + k4 + e] = (_Float16)W[(size_t)(k4 + e) * 256 + n0 + n];
    }
    __syncthreads();

    const int lane = tid & 63;
    const int wid  = tid >> 6;
    const int ln15 = lane & 15;
    const int kgrp = lane >> 4;
    const int mw   = wid * 16;                 // wave's m-slice
    const int kfr  = kgrp * 8;                 // lane k base within chunk

    f32x4 acc[4] = {{0.f,0.f,0.f,0.f},{0.f,0.f,0.f,0.f},
                    {0.f,0.f,0.f,0.f},{0.f,0.f,0.f,0.f}};
#pragma unroll
    for (int kc = 0; kc < 8; ++kc) {
        f16x8 af = *reinterpret_cast<const f16x8*>(&As[(mw + ln15) * LDP + kc * 32 + kfr]);
#pragma unroll
        for (int nt = 0; nt < 4; ++nt) {
            f16x8 bf = *reinterpret_cast<const f16x8*>(&Ws[(nt * 16 + ln15) * LDP + kc * 32 + kfr]);
            acc[nt] = __builtin_amdgcn_mfma_f32_16x16x32_f16(af, bf, acc[nt], 0, 0, 0);
        }
    }

#pragma unroll
    for (int nt = 0; nt < 4; ++nt) {
        const int col = n0 + nt * 16 + ln15;
        const float bv = bia[col];
#pragma unroll
        for (int r = 0; r < 4; ++r) {
            const int row = m0 + mw + kgrp * 4 + r;
            float o = fmaxf(acc[nt][r] + bv, 0.f);
            if (resid) o += resid[(size_t)row * 256 + col];
            C[(size_t)row * 256 + col] = o;
        }
    }
}

// ---------------------------------------------------------------- fused attention
// One block = (b,h) x 32 q-rows. Streams K/V in j-blocks of 128 through LDS,
// computes S = qk*SCALE + log(geo+1e-6) (masked), online softmax, accumulates
// O = P@V. Replaces k_score + k_softmax + k_pv.
__global__ __launch_bounds__(256) void k_attn(const float* __restrict__ q,
                                              const float* __restrict__ kk,
                                              const float* __restrict__ vv,
                                              const __half* __restrict__ geo,
                                              const int* __restrict__ mask,
                                              float* __restrict__ y, int l) {
    const int bh = blockIdx.y;
    const int b = bh >> 3, h = bh & 7;
    const int i0t = blockIdx.x * 32;

    __shared__ float Qs[32][36];
    __shared__ float Kst[32][132];   // [d][j] transposed
    __shared__ float Vs[128][36];
    __shared__ float Ps[32][132];
    __shared__ float rowc[32], rowl[32];

    const int tid = threadIdx.x;
    const int tx = tid & 31, ty = tid >> 5;
    const int si0 = ty * 4, sj0 = tx * 4;
    const int prow = tid >> 3, pd4 = (tid & 7) * 4;

    {   // load Q tile
        int i = tid >> 3, d4 = (tid & 7) * 4;
        *reinterpret_cast<float4*>(&Qs[i][d4]) = *reinterpret_cast<const float4*>(
            &q[(size_t)(b * NNq + i0t + i) * DDm + h * DHh + d4]);
    }

    float m_r[4], l_r[4];
#pragma unroll
    for (int e = 0; e < 4; ++e) { m_r[e] = -3.0e38f; l_r[e] = 0.f; }
    float4 oacc = make_float4(0.f, 0.f, 0.f, 0.f);

    const size_t plane = (size_t)NNq * NNq;
    const size_t geo_base = (size_t)((l * 8 + h) * BB + b) * plane;

    for (int jb = 0; jb < 4; ++jb) {
        const int j0t = jb * 128;
        __syncthreads();
#pragma unroll
        for (int r = 0; r < 4; ++r) {   // K transposed
            int idx = r * 256 + tid;
            int j = idx >> 3, d4 = (idx & 7) * 4;
            float4 kv = *reinterpret_cast<const float4*>(
                &kk[(size_t)(b * NNq + j0t + j) * DDm + h * DHh + d4]);
            Kst[d4 + 0][j] = kv.x; Kst[d4 + 1][j] = kv.y;
            Kst[d4 + 2][j] = kv.z; Kst[d4 + 3][j] = kv.w;
        }
#pragma unroll
        for (int r = 0; r < 4; ++r) {   // V
            int idx = r * 256 + tid;
            int j = idx >> 3, d4 = (idx & 7) * 4;
            *reinterpret_cast<float4*>(&Vs[j][d4]) = *reinterpret_cast<const float4*>(
                &vv[(size_t)(b * NNq + j0t + j) * DDm + h * DHh + d4]);
        }
        __syncthreads();

        float acc[4][4] = {};
#pragma unroll 8
        for (int d = 0; d < 32; ++d) {
            float4 kv = *reinterpret_cast<const float4*>(&Kst[d][sj0]);
#pragma unroll
            for (int e = 0; e < 4; ++e) {
                float a = Qs[si0 + e][d];
                acc[e][0] = fmaf(a, kv.x, acc[e][0]);
                acc[e][1] = fmaf(a, kv.y, acc[e][1]);
                acc[e][2] = fmaf(a, kv.z, acc[e][2]);
                acc[e][3] = fmaf(a, kv.w, acc[e][3]);
            }
        }

#pragma unroll
        for (int e = 0; e < 4; ++e) {
            int ig = i0t + si0 + e;
            int jg = j0t + sj0;
            H4 g4 = *reinterpret_cast<const H4*>(&geo[geo_base + (size_t)ig * NNq + jg]);
            int4 mv = *reinterpret_cast<const int4*>(&mask[(size_t)(b * NNq + ig) * NNq + jg]);
            float4 sv;
            sv.x = acc[e][0] * SCALE + __logf(__half2float(g4.a) + 1e-6f);
            sv.y = acc[e][1] * SCALE + __logf(__half2float(g4.b) + 1e-6f);
            sv.z = acc[e][2] * SCALE + __logf(__half2float(g4.c) + 1e-6f);
            sv.w = acc[e][3] * SCALE + __logf(__half2float(g4.d) + 1e-6f);
            if (mv.x == 0) sv.x = -1e9f;
            if (mv.y == 0) sv.y = -1e9f;
            if (mv.z == 0) sv.z = -1e9f;
            if (mv.w == 0) sv.w = -1e9f;

            float mx = fmaxf(fmaxf(sv.x, sv.y), fmaxf(sv.z, sv.w));
#pragma unroll
            for (int o = 16; o > 0; o >>= 1) mx = fmaxf(mx, __shfl_xor(mx, o, 32));
            float mnew = fmaxf(m_r[e], mx);
            float c = __expf(m_r[e] - mnew);
            sv.x = __expf(sv.x - mnew); sv.y = __expf(sv.y - mnew);
            sv.z = __expf(sv.z - mnew); sv.w = __expf(sv.w - mnew);
            float s4 = sv.x + sv.y + sv.z + sv.w;
#pragma unroll
            for (int o = 16; o > 0; o >>= 1) s4 += __shfl_xor(s4, o, 32);
            l_r[e] = l_r[e] * c + s4;
            m_r[e] = mnew;
            *reinterpret_cast<float4*>(&Ps[si0 + e][sj0]) = sv;
            if (tx == 0) rowc[si0 + e] = c;
        }
        __syncthreads();

        float cr = rowc[prow];
        oacc.x *= cr; oacc.y *= cr; oacc.z *= cr; oacc.w *= cr;
#pragma unroll 8
        for (int j = 0; j < 128; j += 4) {
            float4 p4 = *reinterpret_cast<const float4*>(&Ps[prow][j]);
            float4 v0 = *reinterpret_cast<const float4*>(&Vs[j + 0][pd4]);
            float4 v1 = *reinterpret_cast<const float4*>(&Vs[j + 1][pd4]);
            float4 v2 = *reinterpret_cast<const float4*>(&Vs[j + 2][pd4]);
            float4 v3 = *reinterpret_cast<const float4*>(&Vs[j + 3][pd4]);
            oacc.x = fmaf(p4.x, v0.x, oacc.x); oacc.y = fmaf(p4.x, v0.y, oacc.y);
            oacc.z = fmaf(p4.x, v0.z, oacc.z); oacc.w = fmaf(p4.x, v0.w, oacc.w);
            oacc.x = fmaf(p4.y, v1.x, oacc.x); oacc.y = fmaf(p4.y, v1.y, oacc.y);
            oacc.z = fmaf(p4.y, v1.z, oacc.z); oacc.w = fmaf(p4.y, v1.w, oacc.w);
            oacc.x = fmaf(p4.z, v2.x, oacc.x); oacc.y = fmaf(p4.z, v2.y, oacc.y);
            oacc.z = fmaf(p4.z, v2.z, oacc.z); oacc.w = fmaf(p4.z, v2.w, oacc.w);
            oacc.x = fmaf(p4.w, v3.x, oacc.x); oacc.y = fmaf(p4.w, v3.y, oacc.y);
            oacc.z = fmaf(p4.w, v3.z, oacc.z); oacc.w = fmaf(p4.w, v3.w, oacc.w);
        }
    }

    if (tx == 0) {
#pragma unroll
        for (int e = 0; e < 4; ++e) rowl[si0 + e] = l_r[e];
    }
    __syncthreads();
    float inv = 1.0f / rowl[prow];
    oacc.x *= inv; oacc.y *= inv; oacc.z *= inv; oacc.w *= inv;
    *reinterpret_cast<float4*>(&y[(size_t)(b * NNq + i0t + prow) * DDm + h * DHh + pd4]) = oacc;
}

// ---------------------------------------------------------------- launch
extern "C" void kernel_launch(void* const* d_in, const int* in_sizes, int n_in,
                              void* d_out, int out_size, void* d_ws, size_t ws_size,
                              hipStream_t stream) {
    const float* boxes    = (const float*)d_in[0];
    const float* features = (const float*)d_in[1];
    const int*   mask     = (const int*)d_in[2];
    const float* Wq = (const float*)d_in[3];
    const float* bq = (const float*)d_in[4];
    const float* Wk = (const float*)d_in[5];
    const float* bk = (const float*)d_in[6];
    const float* Wv = (const float*)d_in[7];
    const float* bv = (const float*)d_in[8];
    const float* Wo = (const float*)d_in[9];
    const float* bo = (const float*)d_in[10];
    const float* Wg = (const float*)d_in[11];
    const float* bg = (const float*)d_in[12];
    const float* dv = (const float*)d_in[13];

    char* ws = (char*)d_ws;
    float*  boxp = (float*)(ws);                              //    16,384
    __half* geo  = (__half*)(ws + 16384);                     // 25,165,824
    float*  qb   = (float*)(ws + 25182208);                   //  1,048,576
    float*  kb   = (float*)(ws + 26230784);                   //  1,048,576
    float*  vb   = (float*)(ws + 27279360);                   //  1,048,576
    float*  yb   = (float*)(ws + 28327936);                   //  1,048,576  -> ~29.4 MB
    float*  x    = (float*)d_out;

    hipMemcpyAsync(x, features, (size_t)BB * NNq * DDm * sizeof(float),
                   hipMemcpyDeviceToDevice, stream);
    k_boxprep<<<dim3((BB * NNq + 255) / 256), dim3(256), 0, stream>>>(boxes, boxp);
    k_geo<<<dim3(2048), dim3(256), 0, stream>>>(boxp, Wg, bg, dv, geo);

    for (int l = 0; l < LLn; ++l) {
        const float* Wq_l = Wq + (size_t)l * DDm * DDm;
        const float* Wk_l = Wk + (size_t)l * DDm * DDm;
        const float* Wv_l = Wv + (size_t)l * DDm * DDm;
        const float* Wo_l = Wo + (size_t)l * DDm * DDm;
        const float* bq_l = bq + (size_t)l * DDm;
        const float* bk_l = bk + (size_t)l * DDm;
        const float* bv_l = bv + (size_t)l * DDm;
        const float* bo_l = bo + (size_t)l * DDm;

        k_gemm_mfma<<<dim3(16, 4, 3), dim3(256), 0, stream>>>(
            x, Wq_l, Wk_l, Wv_l, bq_l, bk_l, bv_l, qb, kb, vb, nullptr);
        k_attn<<<dim3(16, 16), dim3(256), 0, stream>>>(qb, kb, vb, geo, mask, yb, l);
        k_gemm_mfma<<<dim3(16, 4, 1), dim3(256), 0, stream>>>(
            yb, Wo_l, Wo_l, Wo_l, bo_l, bo_l, bo_l, x, x, x, x);
    }
}